// Round 1
// baseline (10925.550 us; speedup 1.0000x reference)
//
#include <hip/hip_runtime.h>
#include <hip/hip_bf16.h>
#include <math.h>

#define T_ 1024
#define D_ 256
#define N_ 8192
#define NH_ 4
#define NLAYER_ 6
#define VOCAB_ 256

// ---------- helpers ----------

__device__ __forceinline__ float bf2f_raw(unsigned short u) {
    union { unsigned int i; float f; } x;
    x.i = ((unsigned int)u) << 16;
    return x.f;
}

// block-wide sum over 256 threads; returns result to all threads
__device__ __forceinline__ float block_sum(float v, float* red) {
    int tid = threadIdx.x;
    red[tid] = v;
    __syncthreads();
    #pragma unroll
    for (int s = 128; s > 0; s >>= 1) {
        if (tid < s) red[tid] += red[tid + s];
        __syncthreads();
    }
    float r = red[0];
    __syncthreads();
    return r;
}

// ---------- small LN-style kernels (1 block = 1 row of 256) ----------

__global__ void k_embed_ln(const int* __restrict__ idx, const float* __restrict__ ew,
                           float* __restrict__ x) {
    __shared__ float red[256];
    int t = blockIdx.x, d = threadIdx.x;
    float v = ew[idx[t] * D_ + d];
    float mean = block_sum(v, red) * (1.0f / D_);
    float c = v - mean;
    float var = block_sum(c * c, red) * (1.0f / D_);
    x[t * D_ + d] = c * rsqrtf(var + 1e-5f);
}

__global__ void k_ln_rows(float* __restrict__ buf) {
    __shared__ float red[256];
    int r = blockIdx.x, d = threadIdx.x;
    float v = buf[(size_t)r * D_ + d];
    float mean = block_sum(v, red) * (1.0f / D_);
    float c = v - mean;
    float var = block_sum(c * c, red) * (1.0f / D_);
    buf[(size_t)r * D_ + d] = c * rsqrtf(var + 1e-5f);
}

// x = ln(x + ln(ymlp))
__global__ void k_x_update(float* __restrict__ x, const float* __restrict__ ymlp) {
    __shared__ float red[256];
    int t = blockIdx.x, d = threadIdx.x;
    float v = ymlp[t * D_ + d];
    float m1 = block_sum(v, red) * (1.0f / D_);
    float c1 = v - m1;
    float v1 = block_sum(c1 * c1, red) * (1.0f / D_);
    float u = c1 * rsqrtf(v1 + 1e-5f);
    float w = x[t * D_ + d] + u;
    float m2 = block_sum(w, red) * (1.0f / D_);
    float c2 = w - m2;
    float v2 = block_sum(c2 * c2, red) * (1.0f / D_);
    x[t * D_ + d] = c2 * rsqrtf(v2 + 1e-5f);
}

// ---------- projection: A[T,D] (or ykv[h]) @ Bh[D,N], relu epilogue ----------
// MODE 0: out1 = relu bf16 (x_sp), out2 = rope(relu) bf16 (qr)
// MODE 1: out1 = relu * x_sp  bf16 (xy)

template <int MODE>
__global__ __launch_bounds__(256) void k_proj(const float* __restrict__ A,
                                              const float* __restrict__ B,
                                              __hip_bfloat16* __restrict__ out1,
                                              __hip_bfloat16* __restrict__ out2,
                                              const __hip_bfloat16* __restrict__ xsp) {
    const int h = blockIdx.z;
    const int t0 = blockIdx.y * 64;
    const int n0 = blockIdx.x * 64;
    const float* Ah = (MODE == 0) ? A : (A + (size_t)h * T_ * D_);
    const float* Bh = B + (size_t)h * D_ * N_;
    __shared__ __align__(16) float As[16 * 68];
    __shared__ __align__(16) float Bs[16 * 68];
    const int tid = threadIdx.x;
    const int tx = tid & 15, ty = tid >> 4;
    float acc[4][4] = {};
    for (int k0 = 0; k0 < D_; k0 += 16) {
        #pragma unroll
        for (int i = 0; i < 4; i++) {
            int id = tid + i * 256;
            int kk = id & 15, mm = id >> 4;
            As[kk * 68 + mm] = Ah[(t0 + mm) * D_ + k0 + kk];
        }
        #pragma unroll
        for (int i = 0; i < 4; i++) {
            int id = tid + i * 256;
            int nn = id & 63, kk = id >> 6;
            Bs[kk * 68 + nn] = Bh[(size_t)(k0 + kk) * N_ + n0 + nn];
        }
        __syncthreads();
        #pragma unroll
        for (int kk = 0; kk < 16; kk++) {
            const float4 av = *reinterpret_cast<const float4*>(&As[kk * 68 + ty * 4]);
            const float4 bv = *reinterpret_cast<const float4*>(&Bs[kk * 68 + tx * 4]);
            float a[4] = {av.x, av.y, av.z, av.w};
            float b[4] = {bv.x, bv.y, bv.z, bv.w};
            #pragma unroll
            for (int i = 0; i < 4; i++)
                #pragma unroll
                for (int j = 0; j < 4; j++)
                    acc[i][j] = fmaf(a[i], b[j], acc[i][j]);
        }
        __syncthreads();
    }
    if (MODE == 0) {
        #pragma unroll
        for (int i = 0; i < 4; i++) {
            int tt = t0 + ty * 4 + i;
            size_t rowb = ((size_t)h * T_ + tt) * (size_t)N_;
            #pragma unroll
            for (int jp = 0; jp < 2; jp++) {
                int nn = n0 + tx * 4 + jp * 2;  // even
                float v0 = fmaxf(acc[i][jp * 2 + 0], 0.0f);
                float v1 = fmaxf(acc[i][jp * 2 + 1], 0.0f);
                out1[rowb + nn] = __float2bfloat16(v0);
                out1[rowb + nn + 1] = __float2bfloat16(v1);
                // freq = 2^(-nn/512) / (2*pi); phase = frac(t*freq)*2pi
                float freq = exp2f((float)nn * (-1.0f / 512.0f)) * 0.15915494309189535f;
                float ph = (float)tt * freq;
                ph -= floorf(ph);
                float s, c;
                __sincosf(ph * 6.283185307179586f, &s, &c);
                out2[rowb + nn] = __float2bfloat16(v0 * c - v1 * s);
                out2[rowb + nn + 1] = __float2bfloat16(v1 * c + v0 * s);
            }
        }
    } else {
        #pragma unroll
        for (int i = 0; i < 4; i++) {
            int tt = t0 + ty * 4 + i;
            size_t rowb = ((size_t)h * T_ + tt) * (size_t)N_;
            #pragma unroll
            for (int j = 0; j < 4; j++) {
                int nn = n0 + tx * 4 + j;
                float v = fmaxf(acc[i][j], 0.0f);
                float xs = __bfloat162float(xsp[rowb + nn]);
                out1[rowb + nn] = __float2bfloat16(v * xs);
            }
        }
    }
}

// ---------- scores: qr[h] @ qr[h]^T, strict lower triangular ----------

__global__ __launch_bounds__(256) void k_scores(const __hip_bfloat16* __restrict__ qr,
                                                float* __restrict__ sc) {
    const int h = blockIdx.z;
    const int t0 = blockIdx.y * 64;
    const int s0 = blockIdx.x * 64;
    if (s0 > t0) return;  // fully masked tile: never computed, never read
    __shared__ __align__(16) float Qt[32 * 68];
    __shared__ __align__(16) float Qs[32 * 68];
    const int tid = threadIdx.x;
    const int tx = tid & 15, ty = tid >> 4;
    const unsigned short* qh = (const unsigned short*)(qr + (size_t)h * T_ * N_);
    float acc[4][4] = {};
    for (int k0 = 0; k0 < N_; k0 += 32) {
        #pragma unroll
        for (int i = 0; i < 4; i++) {
            int id = (tid + i * 256) * 2;  // element index, even
            int kk = id & 31, mm = id >> 5;
            ushort2 p = *reinterpret_cast<const ushort2*>(&qh[(size_t)(t0 + mm) * N_ + k0 + kk]);
            Qt[kk * 68 + mm] = bf2f_raw(p.x);
            Qt[(kk + 1) * 68 + mm] = bf2f_raw(p.y);
            ushort2 p2 = *reinterpret_cast<const ushort2*>(&qh[(size_t)(s0 + mm) * N_ + k0 + kk]);
            Qs[kk * 68 + mm] = bf2f_raw(p2.x);
            Qs[(kk + 1) * 68 + mm] = bf2f_raw(p2.y);
        }
        __syncthreads();
        #pragma unroll
        for (int kk = 0; kk < 32; kk++) {
            const float4 av = *reinterpret_cast<const float4*>(&Qt[kk * 68 + ty * 4]);
            const float4 bv = *reinterpret_cast<const float4*>(&Qs[kk * 68 + tx * 4]);
            float a[4] = {av.x, av.y, av.z, av.w};
            float b[4] = {bv.x, bv.y, bv.z, bv.w};
            #pragma unroll
            for (int i = 0; i < 4; i++)
                #pragma unroll
                for (int j = 0; j < 4; j++)
                    acc[i][j] = fmaf(a[i], b[j], acc[i][j]);
        }
        __syncthreads();
    }
    #pragma unroll
    for (int i = 0; i < 4; i++) {
        int tt = t0 + ty * 4 + i;
        #pragma unroll
        for (int j = 0; j < 4; j++) {
            int ss = s0 + tx * 4 + j;
            sc[((size_t)h * T_ + tt) * T_ + ss] = (ss < tt) ? acc[i][j] : 0.0f;
        }
    }
}

// ---------- ykv: scores[h] @ x  (K bounded by causal structure) ----------

__global__ __launch_bounds__(256) void k_ykv(const float* __restrict__ sc,
                                             const float* __restrict__ x,
                                             float* __restrict__ ykv) {
    const int h = blockIdx.z;
    const int tIdx = blockIdx.y;
    const int t0 = tIdx * 64;
    const int d0 = blockIdx.x * 64;
    __shared__ __align__(16) float Ss[16 * 68];
    __shared__ __align__(16) float Xs[16 * 68];
    const int tid = threadIdx.x;
    const int tx = tid & 15, ty = tid >> 4;
    const float* sch = sc + (size_t)h * T_ * T_;
    float acc[4][4] = {};
    const int send = (tIdx + 1) * 64;  // only tiles at/below diagonal were written
    for (int s0 = 0; s0 < send; s0 += 16) {
        #pragma unroll
        for (int i = 0; i < 4; i++) {
            int id = tid + i * 256;
            int kk = id & 15, mm = id >> 4;
            Ss[kk * 68 + mm] = sch[(size_t)(t0 + mm) * T_ + s0 + kk];
        }
        #pragma unroll
        for (int i = 0; i < 4; i++) {
            int id = tid + i * 256;
            int dd = id & 63, kk = id >> 6;
            Xs[kk * 68 + dd] = x[(s0 + kk) * D_ + d0 + dd];
        }
        __syncthreads();
        #pragma unroll
        for (int kk = 0; kk < 16; kk++) {
            const float4 av = *reinterpret_cast<const float4*>(&Ss[kk * 68 + ty * 4]);
            const float4 bv = *reinterpret_cast<const float4*>(&Xs[kk * 68 + tx * 4]);
            float a[4] = {av.x, av.y, av.z, av.w};
            float b[4] = {bv.x, bv.y, bv.z, bv.w};
            #pragma unroll
            for (int i = 0; i < 4; i++)
                #pragma unroll
                for (int j = 0; j < 4; j++)
                    acc[i][j] = fmaf(a[i], b[j], acc[i][j]);
        }
        __syncthreads();
    }
    #pragma unroll
    for (int i = 0; i < 4; i++)
        #pragma unroll
        for (int j = 0; j < 4; j++)
            ykv[((size_t)h * T_ + t0 + ty * 4 + i) * D_ + d0 + tx * 4 + j] = acc[i][j];
}

// ---------- ymlp: sum_h xy[h] @ dec[h]  (split-K with atomics) ----------

__global__ __launch_bounds__(256) void k_ymlp(const __hip_bfloat16* __restrict__ xy,
                                              const float* __restrict__ dec,
                                              float* __restrict__ ymlp) {
    const int slice = blockIdx.z;  // 0..7
    const int h = slice >> 1;
    const int nbase = (slice & 1) * (N_ / 2);
    const int t0 = blockIdx.y * 64;
    const int d0 = blockIdx.x * 64;
    __shared__ __align__(16) float Xs[16 * 68];
    __shared__ __align__(16) float Ds[16 * 68];
    const int tid = threadIdx.x;
    const int tx = tid & 15, ty = tid >> 4;
    const __hip_bfloat16* xyh = xy + (size_t)h * T_ * N_;
    const float* dech = dec + (size_t)h * N_ * D_;
    float acc[4][4] = {};
    for (int n0 = nbase; n0 < nbase + N_ / 2; n0 += 16) {
        #pragma unroll
        for (int i = 0; i < 4; i++) {
            int id = tid + i * 256;
            int kk = id & 15, mm = id >> 4;
            Xs[kk * 68 + mm] = __bfloat162float(xyh[(size_t)(t0 + mm) * N_ + n0 + kk]);
        }
        #pragma unroll
        for (int i = 0; i < 4; i++) {
            int id = tid + i * 256;
            int dd = id & 63, kk = id >> 6;
            Ds[kk * 68 + dd] = dech[(size_t)(n0 + kk) * D_ + d0 + dd];
        }
        __syncthreads();
        #pragma unroll
        for (int kk = 0; kk < 16; kk++) {
            const float4 av = *reinterpret_cast<const float4*>(&Xs[kk * 68 + ty * 4]);
            const float4 bv = *reinterpret_cast<const float4*>(&Ds[kk * 68 + tx * 4]);
            float a[4] = {av.x, av.y, av.z, av.w};
            float b[4] = {bv.x, bv.y, bv.z, bv.w};
            #pragma unroll
            for (int i = 0; i < 4; i++)
                #pragma unroll
                for (int j = 0; j < 4; j++)
                    acc[i][j] = fmaf(a[i], b[j], acc[i][j]);
        }
        __syncthreads();
    }
    #pragma unroll
    for (int i = 0; i < 4; i++)
        #pragma unroll
        for (int j = 0; j < 4; j++)
            atomicAdd(&ymlp[(t0 + ty * 4 + i) * D_ + d0 + tx * 4 + j], acc[i][j]);
}

// ---------- lm_head: x[T,D] @ W[D,V] ----------

__global__ __launch_bounds__(256) void k_lmhead(const float* __restrict__ x,
                                                const float* __restrict__ W,
                                                float* __restrict__ out) {
    const int t0 = blockIdx.y * 64;
    const int v0 = blockIdx.x * 64;
    __shared__ __align__(16) float As[16 * 68];
    __shared__ __align__(16) float Bs[16 * 68];
    const int tid = threadIdx.x;
    const int tx = tid & 15, ty = tid >> 4;
    float acc[4][4] = {};
    for (int k0 = 0; k0 < D_; k0 += 16) {
        #pragma unroll
        for (int i = 0; i < 4; i++) {
            int id = tid + i * 256;
            int kk = id & 15, mm = id >> 4;
            As[kk * 68 + mm] = x[(t0 + mm) * D_ + k0 + kk];
        }
        #pragma unroll
        for (int i = 0; i < 4; i++) {
            int id = tid + i * 256;
            int nn = id & 63, kk = id >> 6;
            Bs[kk * 68 + nn] = W[(k0 + kk) * VOCAB_ + v0 + nn];
        }
        __syncthreads();
        #pragma unroll
        for (int kk = 0; kk < 16; kk++) {
            const float4 av = *reinterpret_cast<const float4*>(&As[kk * 68 + ty * 4]);
            const float4 bv = *reinterpret_cast<const float4*>(&Bs[kk * 68 + tx * 4]);
            float a[4] = {av.x, av.y, av.z, av.w};
            float b[4] = {bv.x, bv.y, bv.z, bv.w};
            #pragma unroll
            for (int i = 0; i < 4; i++)
                #pragma unroll
                for (int j = 0; j < 4; j++)
                    acc[i][j] = fmaf(a[i], b[j], acc[i][j]);
        }
        __syncthreads();
    }
    #pragma unroll
    for (int i = 0; i < 4; i++)
        #pragma unroll
        for (int j = 0; j < 4; j++)
            out[(t0 + ty * 4 + i) * VOCAB_ + v0 + tx * 4 + j] = acc[i][j];
}

// ---------- launch ----------

extern "C" void kernel_launch(void* const* d_in, const int* in_sizes, int n_in,
                              void* d_out, int out_size, void* d_ws, size_t ws_size,
                              hipStream_t stream) {
    const int* idx = (const int*)d_in[0];
    const float* embed_w = (const float*)d_in[1];
    const float* encoder = (const float*)d_in[2];
    const float* encoder_v = (const float*)d_in[3];
    const float* decoder = (const float*)d_in[4];
    const float* lm_head = (const float*)d_in[5];
    float* out = (float*)d_out;

    char* p = (char*)d_ws;
    float* x = (float*)p;            p += (size_t)T_ * D_ * 4;
    float* ymlp = (float*)p;         p += (size_t)T_ * D_ * 4;
    float* ykv = (float*)p;          p += (size_t)NH_ * T_ * D_ * 4;
    float* scores = (float*)p;       p += (size_t)NH_ * T_ * T_ * 4;
    __hip_bfloat16* xsp = (__hip_bfloat16*)p; p += (size_t)NH_ * T_ * N_ * 2;
    __hip_bfloat16* qr = (__hip_bfloat16*)p;  p += (size_t)NH_ * T_ * N_ * 2;  // reused as xy

    k_embed_ln<<<T_, 256, 0, stream>>>(idx, embed_w, x);
    for (int l = 0; l < NLAYER_; l++) {
        k_proj<0><<<dim3(N_ / 64, T_ / 64, NH_), 256, 0, stream>>>(x, encoder, xsp, qr, nullptr);
        k_scores<<<dim3(T_ / 64, T_ / 64, NH_), 256, 0, stream>>>(qr, scores);
        k_ykv<<<dim3(D_ / 64, T_ / 64, NH_), 256, 0, stream>>>(scores, x, ykv);
        k_ln_rows<<<NH_ * T_, 256, 0, stream>>>(ykv);
        k_proj<1><<<dim3(N_ / 64, T_ / 64, NH_), 256, 0, stream>>>(ykv, encoder_v, qr /*xy out*/,
                                                                   nullptr, xsp);
        hipMemsetAsync(ymlp, 0, (size_t)T_ * D_ * 4, stream);
        k_ymlp<<<dim3(D_ / 64, T_ / 64, 8), 256, 0, stream>>>(qr, decoder, ymlp);
        k_x_update<<<T_, 256, 0, stream>>>(x, ymlp);
    }
    k_lmhead<<<dim3(VOCAB_ / 64, T_ / 64), 256, 0, stream>>>(x, lm_head, out);
}

// Round 2
// 1946.397 us; speedup vs baseline: 5.6132x; 5.6132x over previous
//
#include <hip/hip_runtime.h>
#include <hip/hip_bf16.h>
#include <math.h>

#define T_ 1024
#define D_ 256
#define N_ 8192
#define NH_ 4
#define NLAYER_ 6
#define VOCAB_ 256
#define TWO_PI_F 6.283185307179586f

typedef __attribute__((ext_vector_type(8))) short short8;
typedef __attribute__((ext_vector_type(4))) float floatx4;
typedef unsigned short ushort_t;

// ---------- async global->LDS 16B ----------
__device__ __forceinline__ void cp16(const void* g, void* l) {
    __builtin_amdgcn_global_load_lds((const __attribute__((address_space(1))) unsigned int*)g,
                                     (__attribute__((address_space(3))) unsigned int*)l,
                                     16, 0, 0);
}

// ---------- block reduce ----------
__device__ __forceinline__ float block_sum(float v, float* red) {
    int tid = threadIdx.x;
    red[tid] = v;
    __syncthreads();
    #pragma unroll
    for (int s = 128; s > 0; s >>= 1) {
        if (tid < s) red[tid] += red[tid + s];
        __syncthreads();
    }
    float r = red[0];
    __syncthreads();
    return r;
}

// ---------- LN kernels ----------

__global__ void k_embed_ln(const int* __restrict__ idx, const float* __restrict__ ew,
                           float* __restrict__ x, __hip_bfloat16* __restrict__ x_bf) {
    __shared__ float red[256];
    int t = blockIdx.x, d = threadIdx.x;
    float v = ew[idx[t] * D_ + d];
    float mean = block_sum(v, red) * (1.0f / D_);
    float c = v - mean;
    float var = block_sum(c * c, red) * (1.0f / D_);
    float o = c * rsqrtf(var + 1e-5f);
    x[t * D_ + d] = o;
    x_bf[t * D_ + d] = __float2bfloat16(o);
}

// LN ykv rows fp32 -> bf16
__global__ void k_ln_rows(const float* __restrict__ in, __hip_bfloat16* __restrict__ outb) {
    __shared__ float red[256];
    int r = blockIdx.x, d = threadIdx.x;
    float v = in[(size_t)r * D_ + d];
    float mean = block_sum(v, red) * (1.0f / D_);
    float c = v - mean;
    float var = block_sum(c * c, red) * (1.0f / D_);
    outb[(size_t)r * D_ + d] = __float2bfloat16(c * rsqrtf(var + 1e-5f));
}

// x = ln(x + ln(ymlp)); also emit bf16
__global__ void k_x_update(float* __restrict__ x, const float* __restrict__ ymlp,
                           __hip_bfloat16* __restrict__ x_bf) {
    __shared__ float red[256];
    int t = blockIdx.x, d = threadIdx.x;
    float v = ymlp[t * D_ + d];
    float m1 = block_sum(v, red) * (1.0f / D_);
    float c1 = v - m1;
    float v1 = block_sum(c1 * c1, red) * (1.0f / D_);
    float u = c1 * rsqrtf(v1 + 1e-5f);
    float w = x[t * D_ + d] + u;
    float m2 = block_sum(w, red) * (1.0f / D_);
    float c2 = w - m2;
    float v2 = block_sum(c2 * c2, red) * (1.0f / D_);
    float o = c2 * rsqrtf(v2 + 1e-5f);
    x[t * D_ + d] = o;
    x_bf[t * D_ + d] = __float2bfloat16(o);
}

// ---------- transpose+convert: in fp32 [h][R][C] -> out bf16 [h][C][R] ----------
__global__ __launch_bounds__(256) void k_tcvt(const float* __restrict__ in,
                                              __hip_bfloat16* __restrict__ out,
                                              int R, int C) {
    int h = blockIdx.z;
    int r0 = blockIdx.y * 32, c0 = blockIdx.x * 32;
    __shared__ float tile[32][33];
    int tx = threadIdx.x & 31, ty = threadIdx.x >> 5;
    const float* inh = in + (size_t)h * R * C;
    __hip_bfloat16* outh = out + (size_t)h * R * C;
    #pragma unroll
    for (int i = 0; i < 4; i++)
        tile[ty + 8 * i][tx] = inh[(size_t)(r0 + ty + 8 * i) * C + c0 + tx];
    __syncthreads();
    #pragma unroll
    for (int i = 0; i < 4; i++)
        outh[(size_t)(c0 + ty + 8 * i) * R + r0 + tx] = __float2bfloat16(tile[tx][ty + 8 * i]);
}

// ---------- core: 64x64 A·B^T bf16 MFMA tile, XOR-swizzled LDS ----------
// A, B: bf16 row-major (raw ushort), 64 rows each, K multiple of 64.
// acc[mi][ni]: wave (wid) computes 32x32 at (wm*32, wn*32).
__device__ __forceinline__ void gemm64(const ushort_t* __restrict__ A,
                                       const ushort_t* __restrict__ B,
                                       int lda, int ldb, int K,
                                       ushort_t* As, ushort_t* Bs,
                                       floatx4 acc[2][2]) {
    const int tid = threadIdx.x;
    const int lane = tid & 63, wid = tid >> 6;
    const int wm = wid >> 1, wn = wid & 1;
    const int quad = lane >> 4, col = lane & 15;
    // staging slots: slot s = p*256 + tid; row = s>>3; phys chunk = s&7;
    // logical chunk c = pc ^ (row&7)  (XOR swizzle, involutive)
    const int sr0 = tid >> 3, spc0 = tid & 7, sc0 = spc0 ^ (sr0 & 7);
    const int s1 = 256 + tid;
    const int sr1 = s1 >> 3, spc1 = s1 & 7, sc1 = spc1 ^ (sr1 & 7);
    ushort_t* lA0 = As + (size_t)(wid * 64) * 8;          // + lane*8 by HW
    ushort_t* lA1 = As + (size_t)(256 + wid * 64) * 8;
    ushort_t* lB0 = Bs + (size_t)(wid * 64) * 8;
    ushort_t* lB1 = Bs + (size_t)(256 + wid * 64) * 8;

    for (int k0 = 0; k0 < K; k0 += 64) {
        cp16(A + (size_t)sr0 * lda + k0 + sc0 * 8, lA0);
        cp16(A + (size_t)sr1 * lda + k0 + sc1 * 8, lA1);
        cp16(B + (size_t)sr0 * ldb + k0 + sc0 * 8, lB0);
        cp16(B + (size_t)sr1 * ldb + k0 + sc1 * 8, lB1);
        __syncthreads();
        #pragma unroll
        for (int kk = 0; kk < 2; kk++) {
            short8 af[2], bf[2];
            #pragma unroll
            for (int mi = 0; mi < 2; mi++) {
                int row = wm * 32 + mi * 16 + col;
                int pc = ((kk << 2) + quad) ^ (row & 7);
                af[mi] = *(const short8*)&As[row * 64 + pc * 8];
            }
            #pragma unroll
            for (int ni = 0; ni < 2; ni++) {
                int row = wn * 32 + ni * 16 + col;
                int pc = ((kk << 2) + quad) ^ (row & 7);
                bf[ni] = *(const short8*)&Bs[row * 64 + pc * 8];
            }
            #pragma unroll
            for (int mi = 0; mi < 2; mi++)
                #pragma unroll
                for (int ni = 0; ni < 2; ni++)
                    acc[mi][ni] = __builtin_amdgcn_mfma_f32_16x16x32_bf16(
                        af[mi], bf[ni], acc[mi][ni], 0, 0, 0);
        }
        __syncthreads();
    }
}

// ---------- scores: qr @ qr^T, strict lower ----------
__global__ __launch_bounds__(256) void k_scores_m(const __hip_bfloat16* __restrict__ qr,
                                                  float* __restrict__ sc) {
    const int h = blockIdx.z;
    const int t0 = blockIdx.y * 64, s0 = blockIdx.x * 64;
    if (s0 > t0) return;
    __shared__ __align__(16) ushort_t As[64 * 64];
    __shared__ __align__(16) ushort_t Bs[64 * 64];
    const ushort_t* qh = (const ushort_t*)qr + (size_t)h * T_ * N_;
    floatx4 acc[2][2];
    #pragma unroll
    for (int mi = 0; mi < 2; mi++)
        #pragma unroll
        for (int ni = 0; ni < 2; ni++) acc[mi][ni] = (floatx4){0.f, 0.f, 0.f, 0.f};
    gemm64(qh + (size_t)t0 * N_, qh + (size_t)s0 * N_, N_, N_, N_, As, Bs, acc);
    const int tid = threadIdx.x, lane = tid & 63, wid = tid >> 6;
    const int wm = wid >> 1, wn = wid & 1, quad = lane >> 4, col = lane & 15;
    #pragma unroll
    for (int mi = 0; mi < 2; mi++)
        #pragma unroll
        for (int ni = 0; ni < 2; ni++)
            #pragma unroll
            for (int r = 0; r < 4; r++) {
                int tt = t0 + wm * 32 + mi * 16 + quad * 4 + r;
                int ss = s0 + wn * 32 + ni * 16 + col;
                sc[((size_t)h * T_ + tt) * T_ + ss] = (ss < tt) ? acc[mi][ni][r] : 0.0f;
            }
}

// ---------- proj: A_bf[rows,256] @ Wt[h][n][256]^T ----------
// MODE 0: out1 = relu (x_sp), out2 = rope(relu) (qr)
// MODE 1: out1 = relu * xsp  (xy)
template <int MODE>
__global__ __launch_bounds__(256) void k_proj_m(const __hip_bfloat16* __restrict__ Abf,
                                                const __hip_bfloat16* __restrict__ Wt,
                                                __hip_bfloat16* __restrict__ out1,
                                                __hip_bfloat16* __restrict__ out2,
                                                const __hip_bfloat16* __restrict__ xsp) {
    const int h = blockIdx.z;
    const int t0 = blockIdx.y * 64, n0 = blockIdx.x * 64;
    __shared__ __align__(16) ushort_t As[64 * 64];
    __shared__ __align__(16) ushort_t Bs[64 * 64];
    const ushort_t* Ah = (const ushort_t*)Abf + (MODE ? (size_t)h * T_ * D_ : (size_t)0)
                         + (size_t)t0 * D_;
    const ushort_t* Bh = (const ushort_t*)Wt + (size_t)h * N_ * D_ + (size_t)n0 * D_;
    floatx4 acc[2][2];
    #pragma unroll
    for (int mi = 0; mi < 2; mi++)
        #pragma unroll
        for (int ni = 0; ni < 2; ni++) acc[mi][ni] = (floatx4){0.f, 0.f, 0.f, 0.f};
    gemm64(Ah, Bh, D_, D_, D_, As, Bs, acc);
    const int tid = threadIdx.x, lane = tid & 63, wid = tid >> 6;
    const int wm = wid >> 1, wn = wid & 1, quad = lane >> 4, col = lane & 15;
    #pragma unroll
    for (int mi = 0; mi < 2; mi++)
        #pragma unroll
        for (int ni = 0; ni < 2; ni++)
            #pragma unroll
            for (int r = 0; r < 4; r++) {
                int tt = t0 + wm * 32 + mi * 16 + quad * 4 + r;
                int nn = n0 + wn * 32 + ni * 16 + col;
                size_t off = ((size_t)h * T_ + tt) * (size_t)N_ + nn;
                float v = fmaxf(acc[mi][ni][r], 0.0f);
                if (MODE == 0) {
                    float vp = __shfl_xor(v, 1);  // rotate partner (col^1, same row)
                    out1[off] = __float2bfloat16(v);
                    int ne = nn & ~1;
                    float freq = exp2f((float)ne * (-1.0f / 512.0f)) * 0.15915494309189535f;
                    float ph = (float)tt * freq;
                    ph -= floorf(ph);
                    float s, c;
                    __sincosf(ph * TWO_PI_F, &s, &c);
                    float o = (nn & 1) ? (v * c + vp * s) : (v * c - vp * s);
                    out2[off] = __float2bfloat16(o);
                } else {
                    float xs = __bfloat162float(xsp[off]);
                    out1[off] = __float2bfloat16(v * xs);
                }
            }
}

// ---------- ymlp: sum_h xy[h] @ decT[h]^T, split-K x4, atomic fp32 ----------
__global__ __launch_bounds__(256) void k_ymlp_m(const __hip_bfloat16* __restrict__ xy,
                                                const __hip_bfloat16* __restrict__ decT,
                                                float* __restrict__ ymlp) {
    const int z = blockIdx.z;
    const int h = z >> 2, kc = z & 3;
    const int t0 = blockIdx.y * 64, d0 = blockIdx.x * 64;
    const int kbase = kc * (N_ / 4);
    __shared__ __align__(16) ushort_t As[64 * 64];
    __shared__ __align__(16) ushort_t Bs[64 * 64];
    const ushort_t* Ah = (const ushort_t*)xy + (size_t)h * T_ * N_ + (size_t)t0 * N_ + kbase;
    const ushort_t* Bh = (const ushort_t*)decT + (size_t)h * D_ * N_ + (size_t)d0 * N_ + kbase;
    floatx4 acc[2][2];
    #pragma unroll
    for (int mi = 0; mi < 2; mi++)
        #pragma unroll
        for (int ni = 0; ni < 2; ni++) acc[mi][ni] = (floatx4){0.f, 0.f, 0.f, 0.f};
    gemm64(Ah, Bh, N_, N_, N_ / 4, As, Bs, acc);
    const int tid = threadIdx.x, lane = tid & 63, wid = tid >> 6;
    const int wm = wid >> 1, wn = wid & 1, quad = lane >> 4, col = lane & 15;
    #pragma unroll
    for (int mi = 0; mi < 2; mi++)
        #pragma unroll
        for (int ni = 0; ni < 2; ni++)
            #pragma unroll
            for (int r = 0; r < 4; r++) {
                int tt = t0 + wm * 32 + mi * 16 + quad * 4 + r;
                int dd = d0 + wn * 32 + ni * 16 + col;
                atomicAdd(&ymlp[tt * D_ + dd], acc[mi][ni][r]);
            }
}

// ---------- ykv: scores[h] @ x (fp32 vector GEMM, K causal-bounded) ----------
__global__ __launch_bounds__(256) void k_ykv(const float* __restrict__ sc,
                                             const float* __restrict__ x,
                                             float* __restrict__ ykv) {
    const int h = blockIdx.z;
    const int tIdx = blockIdx.y;
    const int t0 = tIdx * 64;
    const int d0 = blockIdx.x * 64;
    __shared__ __align__(16) float Ss[16 * 68];
    __shared__ __align__(16) float Xs[16 * 68];
    const int tid = threadIdx.x;
    const int tx = tid & 15, ty = tid >> 4;
    const float* sch = sc + (size_t)h * T_ * T_;
    float acc[4][4] = {};
    const int send = (tIdx + 1) * 64;
    for (int s0 = 0; s0 < send; s0 += 16) {
        #pragma unroll
        for (int i = 0; i < 4; i++) {
            int id = tid + i * 256;
            int kk = id & 15, mm = id >> 4;
            Ss[kk * 68 + mm] = sch[(size_t)(t0 + mm) * T_ + s0 + kk];
        }
        #pragma unroll
        for (int i = 0; i < 4; i++) {
            int id = tid + i * 256;
            int dd = id & 63, kk = id >> 6;
            Xs[kk * 68 + dd] = x[(s0 + kk) * D_ + d0 + dd];
        }
        __syncthreads();
        #pragma unroll
        for (int kk = 0; kk < 16; kk++) {
            const float4 av = *reinterpret_cast<const float4*>(&Ss[kk * 68 + ty * 4]);
            const float4 bv = *reinterpret_cast<const float4*>(&Xs[kk * 68 + tx * 4]);
            float a[4] = {av.x, av.y, av.z, av.w};
            float b[4] = {bv.x, bv.y, bv.z, bv.w};
            #pragma unroll
            for (int i = 0; i < 4; i++)
                #pragma unroll
                for (int j = 0; j < 4; j++)
                    acc[i][j] = fmaf(a[i], b[j], acc[i][j]);
        }
        __syncthreads();
    }
    #pragma unroll
    for (int i = 0; i < 4; i++)
        #pragma unroll
        for (int j = 0; j < 4; j++)
            ykv[((size_t)h * T_ + t0 + ty * 4 + i) * D_ + d0 + tx * 4 + j] = acc[i][j];
}

// ---------- lm_head: x[T,D] @ W[D,V] fp32 ----------
__global__ __launch_bounds__(256) void k_lmhead(const float* __restrict__ x,
                                                const float* __restrict__ W,
                                                float* __restrict__ out) {
    const int t0 = blockIdx.y * 64;
    const int v0 = blockIdx.x * 64;
    __shared__ __align__(16) float As[16 * 68];
    __shared__ __align__(16) float Bs[16 * 68];
    const int tid = threadIdx.x;
    const int tx = tid & 15, ty = tid >> 4;
    float acc[4][4] = {};
    for (int k0 = 0; k0 < D_; k0 += 16) {
        #pragma unroll
        for (int i = 0; i < 4; i++) {
            int id = tid + i * 256;
            int kk = id & 15, mm = id >> 4;
            As[kk * 68 + mm] = x[(t0 + mm) * D_ + k0 + kk];
        }
        #pragma unroll
        for (int i = 0; i < 4; i++) {
            int id = tid + i * 256;
            int nn = id & 63, kk = id >> 6;
            Bs[kk * 68 + nn] = W[(k0 + kk) * VOCAB_ + v0 + nn];
        }
        __syncthreads();
        #pragma unroll
        for (int kk = 0; kk < 16; kk++) {
            const float4 av = *reinterpret_cast<const float4*>(&As[kk * 68 + ty * 4]);
            const float4 bv = *reinterpret_cast<const float4*>(&Bs[kk * 68 + tx * 4]);
            float a[4] = {av.x, av.y, av.z, av.w};
            float b[4] = {bv.x, bv.y, bv.z, bv.w};
            #pragma unroll
            for (int i = 0; i < 4; i++)
                #pragma unroll
                for (int j = 0; j < 4; j++)
                    acc[i][j] = fmaf(a[i], b[j], acc[i][j]);
        }
        __syncthreads();
    }
    #pragma unroll
    for (int i = 0; i < 4; i++)
        #pragma unroll
        for (int j = 0; j < 4; j++)
            out[(t0 + ty * 4 + i) * VOCAB_ + v0 + tx * 4 + j] = acc[i][j];
}

// ---------- launch ----------

extern "C" void kernel_launch(void* const* d_in, const int* in_sizes, int n_in,
                              void* d_out, int out_size, void* d_ws, size_t ws_size,
                              hipStream_t stream) {
    const int* idx = (const int*)d_in[0];
    const float* embed_w = (const float*)d_in[1];
    const float* encoder = (const float*)d_in[2];
    const float* encoder_v = (const float*)d_in[3];
    const float* decoder = (const float*)d_in[4];
    const float* lm_head = (const float*)d_in[5];
    float* out = (float*)d_out;

    char* p = (char*)d_ws;
    auto alloc = [&](size_t bytes) {
        char* q = p;
        p += (bytes + 255) & ~(size_t)255;
        return q;
    };
    float* x = (float*)alloc((size_t)T_ * D_ * 4);
    __hip_bfloat16* x_bf = (__hip_bfloat16*)alloc((size_t)T_ * D_ * 2);
    float* ymlp = (float*)alloc((size_t)T_ * D_ * 4);
    float* ykv = (float*)alloc((size_t)NH_ * T_ * D_ * 4);
    __hip_bfloat16* ykv_bf = (__hip_bfloat16*)alloc((size_t)NH_ * T_ * D_ * 2);
    float* scores = (float*)alloc((size_t)NH_ * T_ * T_ * 4);
    __hip_bfloat16* xsp = (__hip_bfloat16*)alloc((size_t)NH_ * T_ * N_ * 2);
    __hip_bfloat16* qr = (__hip_bfloat16*)alloc((size_t)NH_ * T_ * N_ * 2);  // reused as xy
    __hip_bfloat16* encT = (__hip_bfloat16*)alloc((size_t)NH_ * N_ * D_ * 2);
    __hip_bfloat16* encvT = (__hip_bfloat16*)alloc((size_t)NH_ * N_ * D_ * 2);
    __hip_bfloat16* decT = (__hip_bfloat16*)alloc((size_t)NH_ * N_ * D_ * 2);

    // one-time weight transposes (bf16): enc [h][D][N] -> [h][N][D]; dec [h][N][D] -> [h][D][N]
    k_tcvt<<<dim3(N_ / 32, D_ / 32, NH_), 256, 0, stream>>>(encoder, encT, D_, N_);
    k_tcvt<<<dim3(N_ / 32, D_ / 32, NH_), 256, 0, stream>>>(encoder_v, encvT, D_, N_);
    k_tcvt<<<dim3(D_ / 32, N_ / 32, NH_), 256, 0, stream>>>(decoder, decT, N_, D_);

    k_embed_ln<<<T_, 256, 0, stream>>>(idx, embed_w, x, x_bf);
    for (int l = 0; l < NLAYER_; l++) {
        k_proj_m<0><<<dim3(N_ / 64, T_ / 64, NH_), 256, 0, stream>>>(x_bf, encT, xsp, qr, nullptr);
        k_scores_m<<<dim3(T_ / 64, T_ / 64, NH_), 256, 0, stream>>>(qr, scores);
        k_ykv<<<dim3(D_ / 64, T_ / 64, NH_), 256, 0, stream>>>(scores, x, ykv);
        k_ln_rows<<<NH_ * T_, 256, 0, stream>>>(ykv, ykv_bf);
        k_proj_m<1><<<dim3(N_ / 64, T_ / 64, NH_), 256, 0, stream>>>(ykv_bf, encvT, qr /*xy*/,
                                                                     nullptr, xsp);
        hipMemsetAsync(ymlp, 0, (size_t)T_ * D_ * 4, stream);
        k_ymlp_m<<<dim3(D_ / 64, T_ / 64, NH_ * 4), 256, 0, stream>>>(qr, decT, ymlp);
        k_x_update<<<T_, 256, 0, stream>>>(x, ymlp, x_bf);
    }
    k_lmhead<<<dim3(VOCAB_ / 64, T_ / 64), 256, 0, stream>>>(x, lm_head, out);
}

// Round 3
// 1687.712 us; speedup vs baseline: 6.4736x; 1.1533x over previous
//
#include <hip/hip_runtime.h>
#include <hip/hip_bf16.h>
#include <math.h>

#define T_ 1024
#define D_ 256
#define N_ 8192
#define NH_ 4
#define NLAYER_ 6
#define VOCAB_ 256
#define TWO_PI_F 6.283185307179586f

typedef __attribute__((ext_vector_type(8))) short short8;
typedef __attribute__((ext_vector_type(4))) float floatx4;
typedef unsigned short ushort_t;

// ---------- async global->LDS 16B ----------
__device__ __forceinline__ void cp16(const void* g, void* l) {
    __builtin_amdgcn_global_load_lds((const __attribute__((address_space(1))) unsigned int*)g,
                                     (__attribute__((address_space(3))) unsigned int*)l,
                                     16, 0, 0);
}

__device__ __forceinline__ float bf2f_raw(unsigned short u) {
    union { unsigned int i; float f; } x;
    x.i = ((unsigned int)u) << 16;
    return x.f;
}
__device__ __forceinline__ unsigned short f2bf_u(float f) {
    union { float f; unsigned int u; } x; x.f = f;
    unsigned int r = (x.u + 0x7fffu + ((x.u >> 16) & 1u)) >> 16;
    return (unsigned short)r;
}

// ---------- block reduce ----------
__device__ __forceinline__ float block_sum(float v, float* red) {
    int tid = threadIdx.x;
    red[tid] = v;
    __syncthreads();
    #pragma unroll
    for (int s = 128; s > 0; s >>= 1) {
        if (tid < s) red[tid] += red[tid + s];
        __syncthreads();
    }
    float r = red[0];
    __syncthreads();
    return r;
}

// ---------- LN kernels ----------

__global__ void k_embed_ln(const int* __restrict__ idx, const float* __restrict__ ew,
                           float* __restrict__ x, __hip_bfloat16* __restrict__ x_bf) {
    __shared__ float red[256];
    int t = blockIdx.x, d = threadIdx.x;
    float v = ew[idx[t] * D_ + d];
    float mean = block_sum(v, red) * (1.0f / D_);
    float c = v - mean;
    float var = block_sum(c * c, red) * (1.0f / D_);
    float o = c * rsqrtf(var + 1e-5f);
    x[t * D_ + d] = o;
    x_bf[t * D_ + d] = __float2bfloat16(o);
}

__global__ void k_ln_rows(const float* __restrict__ in, __hip_bfloat16* __restrict__ outb) {
    __shared__ float red[256];
    int r = blockIdx.x, d = threadIdx.x;
    float v = in[(size_t)r * D_ + d];
    float mean = block_sum(v, red) * (1.0f / D_);
    float c = v - mean;
    float var = block_sum(c * c, red) * (1.0f / D_);
    outb[(size_t)r * D_ + d] = __float2bfloat16(c * rsqrtf(var + 1e-5f));
}

// x = ln(x + ln(sum of 16 ymlp partials)); emit fp32 + bf16
__global__ void k_x_update(float* __restrict__ x, const float* __restrict__ ypart,
                           __hip_bfloat16* __restrict__ x_bf) {
    __shared__ float red[256];
    int t = blockIdx.x, d = threadIdx.x;
    float v = 0.0f;
    #pragma unroll
    for (int i = 0; i < 16; i++) v += ypart[(size_t)i * T_ * D_ + t * D_ + d];
    float m1 = block_sum(v, red) * (1.0f / D_);
    float c1 = v - m1;
    float v1 = block_sum(c1 * c1, red) * (1.0f / D_);
    float u = c1 * rsqrtf(v1 + 1e-5f);
    float w = x[t * D_ + d] + u;
    float m2 = block_sum(w, red) * (1.0f / D_);
    float c2 = w - m2;
    float v2 = block_sum(c2 * c2, red) * (1.0f / D_);
    float o = c2 * rsqrtf(v2 + 1e-5f);
    x[t * D_ + d] = o;
    x_bf[t * D_ + d] = __float2bfloat16(o);
}

// ---------- transpose+convert: fp32 [h][R][C] -> bf16 [h][C][R] ----------
__global__ __launch_bounds__(256) void k_tcvt(const float* __restrict__ in,
                                              __hip_bfloat16* __restrict__ out,
                                              int R, int C) {
    int h = blockIdx.z;
    int r0 = blockIdx.y * 32, c0 = blockIdx.x * 32;
    __shared__ float tile[32][33];
    int tx = threadIdx.x & 31, ty = threadIdx.x >> 5;
    const float* inh = in + (size_t)h * R * C;
    __hip_bfloat16* outh = out + (size_t)h * R * C;
    #pragma unroll
    for (int i = 0; i < 4; i++)
        tile[ty + 8 * i][tx] = inh[(size_t)(r0 + ty + 8 * i) * C + c0 + tx];
    __syncthreads();
    #pragma unroll
    for (int i = 0; i < 4; i++)
        outh[(size_t)(c0 + ty + 8 * i) * R + r0 + tx] = __float2bfloat16(tile[tx][ty + 8 * i]);
}

// ---------- one-time RoPE table: packed (cos,sin) bf16 per (t, n_even/2) ----------
__global__ void k_rope_tab(unsigned int* __restrict__ tab) {
    int idx = blockIdx.x * 256 + threadIdx.x;  // T_ * 4096 entries
    int t = idx >> 12, j = idx & 4095;         // freq = 2^(-j/256) / 2pi
    float freq = exp2f((float)j * (-1.0f / 256.0f)) * 0.15915494309189535f;
    float ph = (float)t * freq;
    ph -= floorf(ph);
    float s, c;
    __sincosf(ph * TWO_PI_F, &s, &c);
    tab[idx] = (unsigned int)f2bf_u(c) | ((unsigned int)f2bf_u(s) << 16);
}

// ---------- core: 128x128 A·B^T bf16 MFMA tile, BK=64, XOR-swizzled LDS ----------
// 256 threads = 4 waves in 2x2; each wave computes 64x64 (4x4 of 16x16).
__device__ __forceinline__ void gemm128(const ushort_t* __restrict__ A,
                                        const ushort_t* __restrict__ B,
                                        int lda, int ldb, int K,
                                        ushort_t* As, ushort_t* Bs,
                                        floatx4 acc[4][4]) {
    const int tid = threadIdx.x;
    const int lane = tid & 63, wid = tid >> 6;
    const int wm = wid >> 1, wn = wid & 1;
    const int quad = lane >> 4, col = lane & 15;
    int srow[4], scol[4];
    #pragma unroll
    for (int i = 0; i < 4; i++) {
        int s = i * 256 + tid;
        srow[i] = s >> 3;
        scol[i] = (s & 7) ^ (srow[i] & 7);  // XOR swizzle (involutive)
    }
    for (int k0 = 0; k0 < K; k0 += 64) {
        #pragma unroll
        for (int i = 0; i < 4; i++)
            cp16(A + (size_t)srow[i] * lda + k0 + scol[i] * 8,
                 As + (size_t)(i * 256 + wid * 64) * 8);
        #pragma unroll
        for (int i = 0; i < 4; i++)
            cp16(B + (size_t)srow[i] * ldb + k0 + scol[i] * 8,
                 Bs + (size_t)(i * 256 + wid * 64) * 8);
        __syncthreads();
        #pragma unroll
        for (int kk = 0; kk < 2; kk++) {
            short8 af[4], bf[4];
            #pragma unroll
            for (int mi = 0; mi < 4; mi++) {
                int row = wm * 64 + mi * 16 + col;
                int pc = ((kk << 2) + quad) ^ (row & 7);
                af[mi] = *(const short8*)&As[row * 64 + pc * 8];
            }
            #pragma unroll
            for (int ni = 0; ni < 4; ni++) {
                int row = wn * 64 + ni * 16 + col;
                int pc = ((kk << 2) + quad) ^ (row & 7);
                bf[ni] = *(const short8*)&Bs[row * 64 + pc * 8];
            }
            #pragma unroll
            for (int mi = 0; mi < 4; mi++)
                #pragma unroll
                for (int ni = 0; ni < 4; ni++)
                    acc[mi][ni] = __builtin_amdgcn_mfma_f32_16x16x32_bf16(
                        af[mi], bf[ni], acc[mi][ni], 0, 0, 0);
        }
        __syncthreads();
    }
}

#define GEMM_PROLOGUE()                                              \
    __shared__ __align__(16) ushort_t As[128 * 64];                  \
    __shared__ __align__(16) ushort_t Bs[128 * 64];                  \
    floatx4 acc[4][4];                                               \
    _Pragma("unroll") for (int mi = 0; mi < 4; mi++)                 \
        _Pragma("unroll") for (int ni = 0; ni < 4; ni++)             \
            acc[mi][ni] = (floatx4){0.f, 0.f, 0.f, 0.f};             \
    const int lane = threadIdx.x & 63, wid = threadIdx.x >> 6;       \
    const int wm = wid >> 1, wn = wid & 1;                           \
    const int quad = lane >> 4, col = lane & 15;

// ---------- scores: qr @ qr^T, 128-tiles on lower triangle, split-K=2, bf16 partials ----------
__global__ __launch_bounds__(256) void k_scores_m(const __hip_bfloat16* __restrict__ qr,
                                                  __hip_bfloat16* __restrict__ scp) {
    int i = blockIdx.x;
    int ti = 0;
    while ((ti + 1) * (ti + 2) / 2 <= i) ti++;
    int si = i - ti * (ti + 1) / 2;
    const int t0 = ti * 128, s0 = si * 128;
    const int ks = blockIdx.y, h = blockIdx.z;
    GEMM_PROLOGUE();
    const ushort_t* qh = (const ushort_t*)qr + (size_t)h * T_ * N_ + (size_t)ks * (N_ / 2);
    gemm128(qh + (size_t)t0 * N_, qh + (size_t)s0 * N_, N_, N_, N_ / 2, As, Bs, acc);
    __hip_bfloat16* sch = scp + (size_t)ks * NH_ * T_ * T_ + (size_t)h * T_ * T_;
    #pragma unroll
    for (int mi = 0; mi < 4; mi++)
        #pragma unroll
        for (int ni = 0; ni < 4; ni++)
            #pragma unroll
            for (int r = 0; r < 4; r++) {
                int tt = t0 + wm * 64 + mi * 16 + quad * 4 + r;
                int ss = s0 + wn * 64 + ni * 16 + col;
                float v = (ss < tt) ? acc[mi][ni][r] : 0.0f;
                sch[(size_t)tt * T_ + ss] = __float2bfloat16(v);
            }
}

// sum the two split-K partials in place (into split 0)
__global__ void k_sc_cvt(__hip_bfloat16* __restrict__ scp) {
    int i = blockIdx.x;
    int ti = 0;
    while ((ti + 1) * (ti + 2) / 2 <= i) ti++;
    int si = i - ti * (ti + 1) / 2;
    const size_t S2 = (size_t)NH_ * T_ * T_;
    size_t b = (size_t)blockIdx.y * T_ * T_;
    for (int e = threadIdx.x; e < 128 * 128; e += 256) {
        int r = e >> 7, c = e & 127;
        size_t off = b + (size_t)(ti * 128 + r) * T_ + si * 128 + c;
        float v = __bfloat162float(scp[off]) + __bfloat162float(scp[off + S2]);
        scp[off] = __float2bfloat16(v);
    }
}

// ---------- proj: A_bf[rows,256] @ Wt[h][n][256]^T, 128-tiles ----------
template <int MODE>
__global__ __launch_bounds__(256) void k_proj_m(const __hip_bfloat16* __restrict__ Abf,
                                                const __hip_bfloat16* __restrict__ Wt,
                                                __hip_bfloat16* __restrict__ out1,
                                                __hip_bfloat16* __restrict__ out2,
                                                const __hip_bfloat16* __restrict__ xsp,
                                                const unsigned int* __restrict__ rtab) {
    const int h = blockIdx.z;
    const int t0 = blockIdx.y * 128, n0 = blockIdx.x * 128;
    GEMM_PROLOGUE();
    const ushort_t* Ah = (const ushort_t*)Abf + (MODE ? (size_t)h * T_ * D_ : (size_t)0)
                         + (size_t)t0 * D_;
    const ushort_t* Bh = (const ushort_t*)Wt + (size_t)h * N_ * D_ + (size_t)n0 * D_;
    gemm128(Ah, Bh, D_, D_, D_, As, Bs, acc);
    #pragma unroll
    for (int mi = 0; mi < 4; mi++)
        #pragma unroll
        for (int ni = 0; ni < 4; ni++)
            #pragma unroll
            for (int r = 0; r < 4; r++) {
                int tt = t0 + wm * 64 + mi * 16 + quad * 4 + r;
                int nn = n0 + wn * 64 + ni * 16 + col;
                size_t off = ((size_t)h * T_ + tt) * (size_t)N_ + nn;
                float v = fmaxf(acc[mi][ni][r], 0.0f);
                if (MODE == 0) {
                    float vp = __shfl_xor(v, 1);  // rotate partner: nn^1 == lane^1
                    out1[off] = __float2bfloat16(v);
                    unsigned int cs = rtab[(size_t)tt * 4096 + (nn >> 1)];
                    float c = bf2f_raw((unsigned short)(cs & 0xffff));
                    float s = bf2f_raw((unsigned short)(cs >> 16));
                    float o = (nn & 1) ? (v * c + vp * s) : (v * c - vp * s);
                    out2[off] = __float2bfloat16(o);
                } else {
                    float xs = __bfloat162float(xsp[off]);
                    out1[off] = __float2bfloat16(v * xs);
                }
            }
}

// ---------- ykv: sc_bf[h] @ xT^T (MFMA), K causal-bounded ----------
__global__ __launch_bounds__(256) void k_ykv_m(const __hip_bfloat16* __restrict__ sc,
                                               const __hip_bfloat16* __restrict__ xT,
                                               float* __restrict__ ykv) {
    const int d0 = blockIdx.x * 128, t0 = blockIdx.y * 128, h = blockIdx.z;
    GEMM_PROLOGUE();
    const ushort_t* Ah = (const ushort_t*)sc + (size_t)h * T_ * T_ + (size_t)t0 * T_;
    const ushort_t* Bh = (const ushort_t*)xT + (size_t)d0 * T_;
    gemm128(Ah, Bh, T_, T_, t0 + 128, As, Bs, acc);
    #pragma unroll
    for (int mi = 0; mi < 4; mi++)
        #pragma unroll
        for (int ni = 0; ni < 4; ni++)
            #pragma unroll
            for (int r = 0; r < 4; r++) {
                int tt = t0 + wm * 64 + mi * 16 + quad * 4 + r;
                int dd = d0 + wn * 64 + ni * 16 + col;
                ykv[((size_t)h * T_ + tt) * D_ + dd] = acc[mi][ni][r];
            }
}

// ---------- ymlp: xy[h] @ decT[h]^T, split-K=4 into 16 partial buffers ----------
__global__ __launch_bounds__(256) void k_ymlp_m(const __hip_bfloat16* __restrict__ xy,
                                                const __hip_bfloat16* __restrict__ decT,
                                                float* __restrict__ ypart) {
    const int d0 = blockIdx.x * 128, t0 = blockIdx.y * 128;
    const int h = blockIdx.z >> 2, ks = blockIdx.z & 3;
    GEMM_PROLOGUE();
    const ushort_t* Ah = (const ushort_t*)xy + (size_t)h * T_ * N_ + (size_t)t0 * N_ + ks * 2048;
    const ushort_t* Bh = (const ushort_t*)decT + (size_t)h * D_ * N_ + (size_t)d0 * N_ + ks * 2048;
    gemm128(Ah, Bh, N_, N_, 2048, As, Bs, acc);
    float* yp = ypart + (size_t)blockIdx.z * T_ * D_;
    #pragma unroll
    for (int mi = 0; mi < 4; mi++)
        #pragma unroll
        for (int ni = 0; ni < 4; ni++)
            #pragma unroll
            for (int r = 0; r < 4; r++) {
                int tt = t0 + wm * 64 + mi * 16 + quad * 4 + r;
                int dd = d0 + wn * 64 + ni * 16 + col;
                yp[(size_t)tt * D_ + dd] = acc[mi][ni][r];
            }
}

// ---------- lm_head: x[T,D] @ W[D,V] fp32 vector ----------
__global__ __launch_bounds__(256) void k_lmhead(const float* __restrict__ x,
                                                const float* __restrict__ W,
                                                float* __restrict__ out) {
    const int t0 = blockIdx.y * 64;
    const int v0 = blockIdx.x * 64;
    __shared__ __align__(16) float Af[16 * 68];
    __shared__ __align__(16) float Bf[16 * 68];
    const int tid = threadIdx.x;
    const int tx = tid & 15, ty = tid >> 4;
    float acc[4][4] = {};
    for (int k0 = 0; k0 < D_; k0 += 16) {
        #pragma unroll
        for (int i = 0; i < 4; i++) {
            int id = tid + i * 256;
            int kk = id & 15, mm = id >> 4;
            Af[kk * 68 + mm] = x[(t0 + mm) * D_ + k0 + kk];
        }
        #pragma unroll
        for (int i = 0; i < 4; i++) {
            int id = tid + i * 256;
            int nn = id & 63, kk = id >> 6;
            Bf[kk * 68 + nn] = W[(k0 + kk) * VOCAB_ + v0 + nn];
        }
        __syncthreads();
        #pragma unroll
        for (int kk = 0; kk < 16; kk++) {
            const float4 av = *reinterpret_cast<const float4*>(&Af[kk * 68 + ty * 4]);
            const float4 bv = *reinterpret_cast<const float4*>(&Bf[kk * 68 + tx * 4]);
            float a[4] = {av.x, av.y, av.z, av.w};
            float b[4] = {bv.x, bv.y, bv.z, bv.w};
            #pragma unroll
            for (int i = 0; i < 4; i++)
                #pragma unroll
                for (int j = 0; j < 4; j++)
                    acc[i][j] = fmaf(a[i], b[j], acc[i][j]);
        }
        __syncthreads();
    }
    #pragma unroll
    for (int i = 0; i < 4; i++)
        #pragma unroll
        for (int j = 0; j < 4; j++)
            out[(t0 + ty * 4 + i) * VOCAB_ + v0 + tx * 4 + j] = acc[i][j];
}

// ---------- launch ----------

extern "C" void kernel_launch(void* const* d_in, const int* in_sizes, int n_in,
                              void* d_out, int out_size, void* d_ws, size_t ws_size,
                              hipStream_t stream) {
    const int* idx = (const int*)d_in[0];
    const float* embed_w = (const float*)d_in[1];
    const float* encoder = (const float*)d_in[2];
    const float* encoder_v = (const float*)d_in[3];
    const float* decoder = (const float*)d_in[4];
    const float* lm_head = (const float*)d_in[5];
    float* out = (float*)d_out;

    char* p = (char*)d_ws;
    auto alloc = [&](size_t bytes) {
        char* q = p;
        p += (bytes + 255) & ~(size_t)255;
        return q;
    };
    float* x = (float*)alloc((size_t)T_ * D_ * 4);
    __hip_bfloat16* x_bf = (__hip_bfloat16*)alloc((size_t)T_ * D_ * 2);
    __hip_bfloat16* xT = (__hip_bfloat16*)alloc((size_t)T_ * D_ * 2);
    float* ykv = (float*)alloc((size_t)NH_ * T_ * D_ * 4);
    __hip_bfloat16* ykv_bf = (__hip_bfloat16*)alloc((size_t)NH_ * T_ * D_ * 2);
    __hip_bfloat16* scp = (__hip_bfloat16*)alloc((size_t)2 * NH_ * T_ * T_ * 2);
    __hip_bfloat16* xsp = (__hip_bfloat16*)alloc((size_t)NH_ * T_ * N_ * 2);
    __hip_bfloat16* qr = (__hip_bfloat16*)alloc((size_t)NH_ * T_ * N_ * 2);  // reused as xy
    __hip_bfloat16* encT = (__hip_bfloat16*)alloc((size_t)NH_ * N_ * D_ * 2);
    __hip_bfloat16* encvT = (__hip_bfloat16*)alloc((size_t)NH_ * N_ * D_ * 2);
    __hip_bfloat16* decT = (__hip_bfloat16*)alloc((size_t)NH_ * N_ * D_ * 2);
    unsigned int* rtab = (unsigned int*)alloc((size_t)T_ * 4096 * 4);
    float* ypart = (float*)xsp;  // alias: ymlp partials live where xsp was (xsp consumed by then)

    // one-time: weight transposes + rope table
    k_tcvt<<<dim3(N_ / 32, D_ / 32, NH_), 256, 0, stream>>>(encoder, encT, D_, N_);
    k_tcvt<<<dim3(N_ / 32, D_ / 32, NH_), 256, 0, stream>>>(encoder_v, encvT, D_, N_);
    k_tcvt<<<dim3(D_ / 32, N_ / 32, NH_), 256, 0, stream>>>(decoder, decT, N_, D_);
    k_rope_tab<<<T_ * 4096 / 256, 256, 0, stream>>>(rtab);

    k_embed_ln<<<T_, 256, 0, stream>>>(idx, embed_w, x, x_bf);
    for (int l = 0; l < NLAYER_; l++) {
        k_proj_m<0><<<dim3(N_ / 128, T_ / 128, NH_), 256, 0, stream>>>(x_bf, encT, xsp, qr,
                                                                       nullptr, rtab);
        k_scores_m<<<dim3(36, 2, NH_), 256, 0, stream>>>(qr, scp);
        k_sc_cvt<<<dim3(36, NH_), 256, 0, stream>>>(scp);
        k_tcvt<<<dim3(D_ / 32, T_ / 32, 1), 256, 0, stream>>>(x, xT, T_, D_);
        k_ykv_m<<<dim3(D_ / 128, T_ / 128, NH_), 256, 0, stream>>>(scp, xT, ykv);
        k_ln_rows<<<NH_ * T_, 256, 0, stream>>>(ykv, ykv_bf);
        k_proj_m<1><<<dim3(N_ / 128, T_ / 128, NH_), 256, 0, stream>>>(ykv_bf, encvT, qr /*xy*/,
                                                                       nullptr, xsp, rtab);
        k_ymlp_m<<<dim3(D_ / 128, T_ / 128, NH_ * 4), 256, 0, stream>>>(qr, decT, ypart);
        k_x_update<<<T_, 256, 0, stream>>>(x, ypart, x_bf);
    }
    k_lmhead<<<dim3(VOCAB_ / 64, T_ / 64), 256, 0, stream>>>(x, lm_head, out);
}